// Round 9
// baseline (75.126 us; speedup 1.0000x reference)
//
#include <hip/hip_runtime.h>

#define HOP      256
#define SAMPLES  262144
#define NBINS    513
#define NFRAMES  1024
#define FPB      16   // frames per tile, one wave per frame

__device__ __forceinline__ float2 cmul(float2 a, float2 b) {
  return make_float2(a.x * b.x - a.y * b.y, a.x * b.y + a.y * b.x);
}
__device__ __forceinline__ float2 lds_ld(const float2* p, int bo) {
  return *(const float2*)((const char*)p + bo);
}
__device__ __forceinline__ void lds_st(float2* p, int bo, float2 v) {
  *(float2*)((char*)p + bo) = v;
}
// swizzle: c = (H<<6)|(M<<3)|L -> (H<<6)|((M^(H&1))<<3)|(L^M)
__device__ __forceinline__ int swz(int c) {
  int H = c >> 6, M = (c >> 3) & 7, L = c & 7;
  return (H << 6) | ((M ^ (H & 1)) << 3) | (L ^ M);
}

// 8-point DFT, natural-order in/out, W = e^{-2pi i/8}
__device__ __forceinline__ void fft8(float2 v[8]) {
  const float R = 0.70710678118654752440f;
  float2 s0 = make_float2(v[0].x + v[4].x, v[0].y + v[4].y);
  float2 d0 = make_float2(v[0].x - v[4].x, v[0].y - v[4].y);
  float2 s1 = make_float2(v[1].x + v[5].x, v[1].y + v[5].y);
  float2 d1 = make_float2(v[1].x - v[5].x, v[1].y - v[5].y);
  float2 s2 = make_float2(v[2].x + v[6].x, v[2].y + v[6].y);
  float2 d2 = make_float2(v[2].x - v[6].x, v[2].y - v[6].y);
  float2 s3 = make_float2(v[3].x + v[7].x, v[3].y + v[7].y);
  float2 d3 = make_float2(v[3].x - v[7].x, v[3].y - v[7].y);
  float2 e1 = make_float2(R * (d1.x + d1.y), R * (d1.y - d1.x));
  float2 e2 = make_float2(d2.y, -d2.x);
  float2 e3 = make_float2(R * (d3.y - d3.x), R * (-d3.x - d3.y));
  float2 p0 = make_float2(s0.x + s2.x, s0.y + s2.y);
  float2 q0 = make_float2(s0.x - s2.x, s0.y - s2.y);
  float2 p1 = make_float2(s1.x + s3.x, s1.y + s3.y);
  float2 q1 = make_float2(s1.x - s3.x, s1.y - s3.y);
  float2 q1t = make_float2(q1.y, -q1.x);
  float2 p2 = make_float2(d0.x + e2.x, d0.y + e2.y);
  float2 q2 = make_float2(d0.x - e2.x, d0.y - e2.y);
  float2 p3 = make_float2(e1.x + e3.x, e1.y + e3.y);
  float2 q3 = make_float2(e1.x - e3.x, e1.y - e3.y);
  float2 q3t = make_float2(q3.y, -q3.x);
  v[0] = make_float2(p0.x + p1.x, p0.y + p1.y);
  v[4] = make_float2(p0.x - p1.x, p0.y - p1.y);
  v[2] = make_float2(q0.x + q1t.x, q0.y + q1t.y);
  v[6] = make_float2(q0.x - q1t.x, q0.y - q1t.y);
  v[1] = make_float2(p2.x + p3.x, p2.y + p3.y);
  v[5] = make_float2(p2.x - p3.x, p2.y - p3.y);
  v[3] = make_float2(q2.x + q3t.x, q2.y + q3t.y);
  v[7] = make_float2(q2.x - q3t.x, q2.y - q3t.y);
}

// unpack one (frame, bin): ZP = frame base, KEY = frame xor-key, SK/SM slots
#define UNPK(ZP, KEY, SK, SM, TW, R1, I1, R2, I2) {                  \
    float2 Zk = lds_ld(ZP, ((SK) ^ (KEY)) << 3);                     \
    float2 Zm = lds_ld(ZP, ((SM) ^ (KEY)) << 3);                     \
    float xer  = 0.5f * (Zk.x + Zm.x);                               \
    float xei  = 0.5f * (Zk.y - Zm.y);                               \
    float xo_r = 0.5f * (Zk.y + Zm.y);                               \
    float xo_i = -0.5f * (Zk.x - Zm.x);                              \
    float ur = (TW).x * xo_r - (TW).y * xo_i;                        \
    float ui = (TW).x * xo_i + (TW).y * xo_r;                        \
    R1 = xer + ur; I1 = xei + ui; R2 = xer - ur; I2 = ui - xei; }

// unpack + store one tile: ZB = LDS buffer base, BK = batch index
#define DO_UNPACK(ZB, BK) {                                              \
    const float2* zp0 = (ZB) + (fu << 9);                                \
    const float2* zp1 = (ZB) + ((fu + 1) << 9);                          \
    const size_t ob = (size_t)(BK) * ((size_t)NBINS * NFRAMES);          \
    {                                                                    \
      float r1a,i1a,r2a,i2a,r1b,i1b,r2b,i2b;                             \
      UNPK(zp0, fu,     sk0, sm0, tw0, r1a, i1a, r2a, i2a)               \
      UNPK(zp1, fu + 1, sk0, sm0, tw0, r1b, i1b, r2b, i2b)               \
      *(float2*)(out_r + ob + qrow) = make_float2(r1a, r1b);             \
      *(float2*)(out_i + ob + qrow) = make_float2(i1a, i1b);             \
      *(float2*)(out_r + ob + mrow) = make_float2(r2a, r2b);             \
      *(float2*)(out_i + ob + mrow) = make_float2(i2a, i2b);             \
    }                                                                    \
    {                                                                    \
      float r1a,i1a,r2a,i2a,r1b,i1b,r2b,i2b;                             \
      UNPK(zp0, fu,     sk1, sm1, tw1, r1a, i1a, r2a, i2a)               \
      UNPK(zp1, fu + 1, sk1, sm1, tw1, r1b, i1b, r2b, i2b)               \
      *(float2*)(out_r + ob + qrow + STP) = make_float2(r1a, r1b);       \
      *(float2*)(out_i + ob + qrow + STP) = make_float2(i1a, i1b);       \
      *(float2*)(out_r + ob + mrow - STP) = make_float2(r2a, r2b);       \
      *(float2*)(out_i + ob + mrow - STP) = make_float2(i2a, i2b);       \
    }                                                                    \
    if (q == 0) {  /* bin 256: X[256] = conj(Z[256]) */                  \
      float2 Za = lds_ld(zp0, (256 ^ fu) << 3);                          \
      float2 Zb = lds_ld(zp1, (256 ^ (fu + 1)) << 3);                    \
      *(float2*)(out_r + ob + erow) = make_float2(Za.x, Zb.x);           \
      *(float2*)(out_i + ob + erow) = make_float2(-Za.y, -Zb.y);         \
    } }

// raw (un-windowed) input load for one frame into R[8]
#define LOAD_X(BK, R) {                                                  \
    const float* xb = x + (size_t)(BK) * SAMPLES;                        \
    if (interior) {                                                      \
      const float2* xc = (const float2*)(xb + base);                     \
      _Pragma("unroll")                                                  \
      for (int n1 = 0; n1 < 8; ++n1) R[n1] = xc[(n1 << 6) + u];          \
    } else {                                                             \
      _Pragma("unroll")                                                  \
      for (int n1 = 0; n1 < 8; ++n1) {                                   \
        int idx = base + (n1 << 7) + 2 * u;                              \
        R[n1] = make_float2(0.f, 0.f);                                   \
        if (idx >= 0 && idx < SAMPLES) R[n1] = *(const float2*)(xb + idx);\
      }                                                                  \
    } }

__global__ __launch_bounds__(1024, 4)   // 1 block/CU (128 KiB LDS), VGPR<=128
void stft_kernel(const float* __restrict__ x, const float* __restrict__ win,
                 float* __restrict__ out) {
  __shared__ float2 z[2 * FPB * 512];   // 128 KiB ping-pong

  const int t    = threadIdx.x;
  const int tile = blockIdx.x & 63;     // frame-window (same for all 4 phases)
  const int bg   = blockIdx.x >> 6;     // batch group 0..3
  const int f0   = tile << 4;
  const bool interior = (tile != 0) && (tile != 63);

  // ---- FFT-role constants ----
  const int w = t >> 6, u = t & 63, g = u >> 3, m2l = u & 7;
  const int A0    = (g << 3) | (m2l ^ g);
  const int B1w_e = (A0 ^ w) << 3;
  const int B1w_o = B1w_e ^ 64;
  const int C1    = (g << 6) | ((g & 1) << 3) | m2l;
  const int B1r   = (C1 ^ w) << 3;
  const int D0    = (g << 6) | ((m2l ^ (g & 1)) << 3) | m2l;
  const int B2r   = (D0 ^ w) << 3;
  const int F0    = (m2l << 3) | (g ^ m2l);
  const int B3_e  = (F0 ^ w) << 3;
  const int B3_o  = B3_e ^ 64;

  // hoisted stage twiddles (lane-only dependence)
  float sn, cs;
  __sincosf((float)u * (-6.28318530717958647693f / 512.f), &sn, &cs);
  const float2 s1w1 = make_float2(cs, sn);
  const float2 s1w2 = cmul(s1w1, s1w1);
  const float2 s1w3 = cmul(s1w2, s1w1);
  const float2 s1w4 = cmul(s1w2, s1w2);
  const float2 s1w5 = cmul(s1w4, s1w1);
  const float2 s1w6 = cmul(s1w4, s1w2);
  const float2 s1w7 = cmul(s1w4, s1w3);
  __sincosf((float)m2l * (-6.28318530717958647693f / 64.f), &sn, &cs);
  const float2 s2w1 = make_float2(cs, sn);
  const float2 s2w2 = cmul(s2w1, s2w1);
  const float2 s2w3 = cmul(s2w2, s2w1);
  const float2 s2w4 = cmul(s2w2, s2w2);
  const float2 s2w5 = cmul(s2w4, s2w1);
  const float2 s2w6 = cmul(s2w4, s2w2);
  const float2 s2w7 = cmul(s2w4, s2w3);

  // ---- unpack-role constants ----
  const int f2i = t & 7, q = t >> 3, fu = f2i << 1;
  const int sk0 = swz(q);
  const int sm0 = swz((512 - q) & 511);
  const int sk1 = sk0 + 128;                    // swz(q+128) = swz(q)+128
  const int sm1 = (q == 0) ? 384 : (sm0 - 128); // swz(384-q)
  __sincosf((float)q * (-6.28318530717958647693f / 1024.f), &sn, &cs);
  const float2 tw0 = make_float2(cs, sn);
  const float2 tw1 = cmul(tw0, make_float2(0.70710678118654752440f,
                                           -0.70710678118654752440f));
  const int fr_u = f0 + fu;
  const size_t qrow = (size_t)q * NFRAMES + fr_u;
  const size_t mrow = (size_t)(512 - q) * NFRAMES + fr_u;
  const size_t erow = (size_t)256 * NFRAMES + fr_u;
  const size_t STP  = (size_t)128 * NFRAMES;
  float* out_r = out;
  float* out_i = out + (size_t)16 * NBINS * NFRAMES;

  // ---- FFT load geometry ----
  const int base = (f0 + w) * HOP - 384;   // pad_left = 384

  // prologue: raw x for phase 0 (batch bg)
  float2 r[8];
  LOAD_X(bg, r)

#pragma unroll
  for (int k = 0; k < 4; ++k) {
    float2* zf = z + ((k & 1) << 13) + (w << 9);

    // window the held samples (win is L1/L2-resident after phase 0)
    float2 rr[8];
#pragma unroll
    for (int n1 = 0; n1 < 8; ++n1) {
      float2 wv = ((const float2*)win)[(n1 << 6) + u];
      rr[n1] = make_float2(r[n1].x * wv.x, r[n1].y * wv.y);
    }
    // prefetch next phase's raw x early (r[] is dead now)
    if (k < 3) LOAD_X(bg + ((k + 1) << 2), r)

    // unpack + store tile k-1 (other buffer) — stores drain under FFT below
    if (k > 0) DO_UNPACK(z + (((k - 1) & 1) << 13), bg + ((k - 1) << 2))

    // FFT tile k into buffer k&1 (all LDS intra-wave, no barrier needed)
    fft8(rr);
    rr[1] = cmul(rr[1], s1w1);
    rr[2] = cmul(rr[2], s1w2);
    rr[3] = cmul(rr[3], s1w3);
    rr[4] = cmul(rr[4], s1w4);
    rr[5] = cmul(rr[5], s1w5);
    rr[6] = cmul(rr[6], s1w6);
    rr[7] = cmul(rr[7], s1w7);
    lds_st(zf, B1w_e,        rr[0]);
    lds_st(zf, B1w_o +  512, rr[1]);
    lds_st(zf, B1w_e + 1024, rr[2]);
    lds_st(zf, B1w_o + 1536, rr[3]);
    lds_st(zf, B1w_e + 2048, rr[4]);
    lds_st(zf, B1w_o + 2560, rr[5]);
    lds_st(zf, B1w_e + 3072, rr[6]);
    lds_st(zf, B1w_o + 3584, rr[7]);

    float2 y[8];
#pragma unroll
    for (int m1 = 0; m1 < 8; ++m1) y[m1] = lds_ld(zf, B1r ^ (72 * m1));
    fft8(y);
    y[1] = cmul(y[1], s2w1);
    y[2] = cmul(y[2], s2w2);
    y[3] = cmul(y[3], s2w3);
    y[4] = cmul(y[4], s2w4);
    y[5] = cmul(y[5], s2w5);
    y[6] = cmul(y[6], s2w6);
    y[7] = cmul(y[7], s2w7);
#pragma unroll
    for (int j1 = 0; j1 < 8; ++j1) lds_st(zf, B1r ^ (72 * j1), y[j1]);

    float2 h[8];
#pragma unroll
    for (int m = 0; m < 8; ++m) h[m] = lds_ld(zf, B2r ^ (m << 3));
    fft8(h);
    lds_st(zf, B3_e,        h[0]);
    lds_st(zf, B3_o +  512, h[1]);
    lds_st(zf, B3_e + 1024, h[2]);
    lds_st(zf, B3_o + 1536, h[3]);
    lds_st(zf, B3_e + 2048, h[4]);
    lds_st(zf, B3_o + 2560, h[5]);
    lds_st(zf, B3_e + 3072, h[6]);
    lds_st(zf, B3_o + 3584, h[7]);

    __syncthreads();
  }

  // epilogue: unpack + store tile 3 (buffer 1, batch bg+12)
  DO_UNPACK(z + (1 << 13), bg + 12)
}

extern "C" void kernel_launch(void* const* d_in, const int* in_sizes, int n_in,
                              void* d_out, int out_size, void* d_ws, size_t ws_size,
                              hipStream_t stream) {
  const float* x = (const float*)d_in[0];
  const float* w = (const float*)d_in[1];
  float* out = (float*)d_out;
  (void)in_sizes; (void)n_in; (void)out_size; (void)d_ws; (void)ws_size;
  stft_kernel<<<dim3(256), dim3(1024), 0, stream>>>(x, w, out);
}

// Round 10
// 37.077 us; speedup vs baseline: 2.0262x; 2.0262x over previous
//
#include <hip/hip_runtime.h>

#define HOP      256
#define SAMPLES  262144
#define NBINS    513
#define NFRAMES  1024

__device__ __forceinline__ float2 cmul(float2 a, float2 b) {
  return make_float2(a.x * b.x - a.y * b.y, a.x * b.y + a.y * b.x);
}
__device__ __forceinline__ float2 lds_ld(const float2* p, int bo) {
  return *(const float2*)((const char*)p + bo);
}
__device__ __forceinline__ void lds_st(float2* p, int bo, float2 v) {
  *(float2*)((char*)p + bo) = v;
}
// swizzle: c = (H<<6)|(M<<3)|L -> (H<<6)|((M^(H&1))<<3)|(L^M)
__device__ __forceinline__ int swz(int c) {
  int H = c >> 6, M = (c >> 3) & 7, L = c & 7;
  return (H << 6) | ((M ^ (H & 1)) << 3) | (L ^ M);
}

// 8-point DFT, natural-order in/out, W = e^{-2pi i/8}
__device__ __forceinline__ void fft8(float2 v[8]) {
  const float R = 0.70710678118654752440f;
  float2 s0 = make_float2(v[0].x + v[4].x, v[0].y + v[4].y);
  float2 d0 = make_float2(v[0].x - v[4].x, v[0].y - v[4].y);
  float2 s1 = make_float2(v[1].x + v[5].x, v[1].y + v[5].y);
  float2 d1 = make_float2(v[1].x - v[5].x, v[1].y - v[5].y);
  float2 s2 = make_float2(v[2].x + v[6].x, v[2].y + v[6].y);
  float2 d2 = make_float2(v[2].x - v[6].x, v[2].y - v[6].y);
  float2 s3 = make_float2(v[3].x + v[7].x, v[3].y + v[7].y);
  float2 d3 = make_float2(v[3].x - v[7].x, v[3].y - v[7].y);
  float2 e1 = make_float2(R * (d1.x + d1.y), R * (d1.y - d1.x));
  float2 e2 = make_float2(d2.y, -d2.x);
  float2 e3 = make_float2(R * (d3.y - d3.x), R * (-d3.x - d3.y));
  float2 p0 = make_float2(s0.x + s2.x, s0.y + s2.y);
  float2 q0 = make_float2(s0.x - s2.x, s0.y - s2.y);
  float2 p1 = make_float2(s1.x + s3.x, s1.y + s3.y);
  float2 q1 = make_float2(s1.x - s3.x, s1.y - s3.y);
  float2 q1t = make_float2(q1.y, -q1.x);
  float2 p2 = make_float2(d0.x + e2.x, d0.y + e2.y);
  float2 q2 = make_float2(d0.x - e2.x, d0.y - e2.y);
  float2 p3 = make_float2(e1.x + e3.x, e1.y + e3.y);
  float2 q3 = make_float2(e1.x - e3.x, e1.y - e3.y);
  float2 q3t = make_float2(q3.y, -q3.x);
  v[0] = make_float2(p0.x + p1.x, p0.y + p1.y);
  v[4] = make_float2(p0.x - p1.x, p0.y - p1.y);
  v[2] = make_float2(q0.x + q1t.x, q0.y + q1t.y);
  v[6] = make_float2(q0.x - q1t.x, q0.y - q1t.y);
  v[1] = make_float2(p2.x + p3.x, p2.y + p3.y);
  v[5] = make_float2(p2.x - p3.x, p2.y - p3.y);
  v[3] = make_float2(q2.x + q3t.x, q2.y + q3t.y);
  v[7] = make_float2(q2.x - q3t.x, q2.y - q3t.y);
}

// unpack one (frame, bin): ZP = frame base, KEY = frame xor-key, SK/SM slots
#define UNPK(ZP, KEY, SK, SM, TW, R1, I1, R2, I2) {                  \
    float2 Zk = lds_ld(ZP, ((SK) ^ (KEY)) << 3);                     \
    float2 Zm = lds_ld(ZP, ((SM) ^ (KEY)) << 3);                     \
    float xer  = 0.5f * (Zk.x + Zm.x);                               \
    float xei  = 0.5f * (Zk.y - Zm.y);                               \
    float xo_r = 0.5f * (Zk.y + Zm.y);                               \
    float xo_i = -0.5f * (Zk.x - Zm.x);                              \
    float ur = (TW).x * xo_r - (TW).y * xo_i;                        \
    float ui = (TW).x * xo_i + (TW).y * xo_r;                        \
    R1 = xer + ur; I1 = xei + ui; R2 = xer - ur; I2 = ui - xei; }

// unpack + store one 16-frame sub-tile: ZB = LDS buffer, OFF = frame offset
#define DO_UNPACK(ZB, OFF) {                                             \
    const float2* zp0 = (ZB) + (fu << 9);                                \
    const float2* zp1 = (ZB) + ((fu + 1) << 9);                          \
    {                                                                    \
      float r1a,i1a,r2a,i2a,r1b,i1b,r2b,i2b;                             \
      UNPK(zp0, fu,     sk0, sm0, tw0, r1a, i1a, r2a, i2a)               \
      UNPK(zp1, fu + 1, sk0, sm0, tw0, r1b, i1b, r2b, i2b)               \
      *(float2*)(out_r + qrow + (OFF)) = make_float2(r1a, r1b);          \
      *(float2*)(out_i + qrow + (OFF)) = make_float2(i1a, i1b);          \
      *(float2*)(out_r + mrow + (OFF)) = make_float2(r2a, r2b);          \
      *(float2*)(out_i + mrow + (OFF)) = make_float2(i2a, i2b);          \
    }                                                                    \
    {                                                                    \
      float r1a,i1a,r2a,i2a,r1b,i1b,r2b,i2b;                             \
      UNPK(zp0, fu,     sk1, sm1, tw1, r1a, i1a, r2a, i2a)               \
      UNPK(zp1, fu + 1, sk1, sm1, tw1, r1b, i1b, r2b, i2b)               \
      *(float2*)(out_r + qrow + STP + (OFF)) = make_float2(r1a, r1b);    \
      *(float2*)(out_i + qrow + STP + (OFF)) = make_float2(i1a, i1b);    \
      *(float2*)(out_r + mrow - STP + (OFF)) = make_float2(r2a, r2b);    \
      *(float2*)(out_i + mrow - STP + (OFF)) = make_float2(i2a, i2b);    \
    }                                                                    \
    if (q == 0) {  /* bin 256: X[256] = conj(Z[256]) */                  \
      float2 Za = lds_ld(zp0, (256 ^ fu) << 3);                          \
      float2 Zb = lds_ld(zp1, (256 ^ (fu + 1)) << 3);                    \
      *(float2*)(out_r + erow + (OFF)) = make_float2(Za.x, Zb.x);        \
      *(float2*)(out_i + erow + (OFF)) = make_float2(-Za.y, -Zb.y);      \
    } }

// windowed load of one frame into R[8]; GUARDED = block-uniform edge flag
#define LOADW(BASE, GUARDED, R) {                                        \
    if (!(GUARDED)) {                                                    \
      const float2* xc = (const float2*)(xb + (BASE));                   \
      _Pragma("unroll")                                                  \
      for (int n1 = 0; n1 < 8; ++n1) {                                   \
        float2 xv = xc[(n1 << 6) + u];                                   \
        float2 wv = wc[(n1 << 6) + u];                                   \
        R[n1] = make_float2(xv.x * wv.x, xv.y * wv.y);                   \
      }                                                                  \
    } else {                                                             \
      _Pragma("unroll")                                                  \
      for (int n1 = 0; n1 < 8; ++n1) {                                   \
        int idx = (BASE) + (n1 << 7) + 2 * u;                            \
        float2 xv = make_float2(0.f, 0.f);                               \
        if (idx >= 0 && idx < SAMPLES) xv = *(const float2*)(xb + idx);  \
        float2 wv = wc[(n1 << 6) + u];                                   \
        R[n1] = make_float2(xv.x * wv.x, xv.y * wv.y);                   \
      }                                                                  \
    } }

// 3-stage radix-8 512-pt FFT of one frame; ZF = this wave's frame base
#define FFT_BODY(ZF, R) {                                                \
    fft8(R);                                                             \
    R[1] = cmul(R[1], s1w1);  R[2] = cmul(R[2], s1w2);                   \
    R[3] = cmul(R[3], s1w3);  R[4] = cmul(R[4], s1w4);                   \
    R[5] = cmul(R[5], s1w5);  R[6] = cmul(R[6], s1w6);                   \
    R[7] = cmul(R[7], s1w7);                                             \
    lds_st(ZF, B1w_e,        R[0]);                                      \
    lds_st(ZF, B1w_o +  512, R[1]);                                      \
    lds_st(ZF, B1w_e + 1024, R[2]);                                      \
    lds_st(ZF, B1w_o + 1536, R[3]);                                      \
    lds_st(ZF, B1w_e + 2048, R[4]);                                      \
    lds_st(ZF, B1w_o + 2560, R[5]);                                      \
    lds_st(ZF, B1w_e + 3072, R[6]);                                      \
    lds_st(ZF, B1w_o + 3584, R[7]);                                      \
    float2 y[8];                                                         \
    _Pragma("unroll")                                                    \
    for (int m1 = 0; m1 < 8; ++m1) y[m1] = lds_ld(ZF, B1r ^ (72 * m1));  \
    fft8(y);                                                             \
    y[1] = cmul(y[1], s2w1);  y[2] = cmul(y[2], s2w2);                   \
    y[3] = cmul(y[3], s2w3);  y[4] = cmul(y[4], s2w4);                   \
    y[5] = cmul(y[5], s2w5);  y[6] = cmul(y[6], s2w6);                   \
    y[7] = cmul(y[7], s2w7);                                             \
    _Pragma("unroll")                                                    \
    for (int j1 = 0; j1 < 8; ++j1) lds_st(ZF, B1r ^ (72 * j1), y[j1]);   \
    float2 h[8];                                                         \
    _Pragma("unroll")                                                    \
    for (int m = 0; m < 8; ++m) h[m] = lds_ld(ZF, B2r ^ (m << 3));       \
    fft8(h);                                                             \
    lds_st(ZF, B3_e,        h[0]);                                       \
    lds_st(ZF, B3_o +  512, h[1]);                                       \
    lds_st(ZF, B3_e + 1024, h[2]);                                       \
    lds_st(ZF, B3_o + 1536, h[3]);                                       \
    lds_st(ZF, B3_e + 2048, h[4]);                                       \
    lds_st(ZF, B3_o + 2560, h[5]);                                       \
    lds_st(ZF, B3_e + 3072, h[6]);                                       \
    lds_st(ZF, B3_o + 3584, h[7]);                                       \
  }

__global__ __launch_bounds__(1024, 4)   // 1 block/CU (128 KiB LDS), VGPR<=128
void stft_kernel(const float* __restrict__ x, const float* __restrict__ win,
                 float* __restrict__ out) {
  __shared__ float2 z[2 * 8192];   // 128 KiB: sub-tile A | sub-tile B

  const int t   = threadIdx.x;
  const int b   = blockIdx.x >> 5;      // batch 0..15
  const int wdw = blockIdx.x & 31;      // 32-frame window 0..31
  const int f0  = wdw << 5;             // first frame of window
  const float* xb = x + (size_t)b * SAMPLES;
  const float2* wc = (const float2*)win;

  // ---- FFT-role constants (wave wid handles frame wid of each sub-tile) ----
  const int wid = t >> 6, u = t & 63, g = u >> 3, m2l = u & 7;
  const int A0    = (g << 3) | (m2l ^ g);
  const int B1w_e = (A0 ^ wid) << 3;
  const int B1w_o = B1w_e ^ 64;
  const int C1    = (g << 6) | ((g & 1) << 3) | m2l;
  const int B1r   = (C1 ^ wid) << 3;
  const int D0    = (g << 6) | ((m2l ^ (g & 1)) << 3) | m2l;
  const int B2r   = (D0 ^ wid) << 3;
  const int F0    = (m2l << 3) | (g ^ m2l);
  const int B3_e  = (F0 ^ wid) << 3;
  const int B3_o  = B3_e ^ 64;

  // hoisted stage twiddles (lane-only dependence; reused by FFT A and B)
  float sn, cs;
  __sincosf((float)u * (-6.28318530717958647693f / 512.f), &sn, &cs);
  const float2 s1w1 = make_float2(cs, sn);
  const float2 s1w2 = cmul(s1w1, s1w1);
  const float2 s1w3 = cmul(s1w2, s1w1);
  const float2 s1w4 = cmul(s1w2, s1w2);
  const float2 s1w5 = cmul(s1w4, s1w1);
  const float2 s1w6 = cmul(s1w4, s1w2);
  const float2 s1w7 = cmul(s1w4, s1w3);
  __sincosf((float)m2l * (-6.28318530717958647693f / 64.f), &sn, &cs);
  const float2 s2w1 = make_float2(cs, sn);
  const float2 s2w2 = cmul(s2w1, s2w1);
  const float2 s2w3 = cmul(s2w2, s2w1);
  const float2 s2w4 = cmul(s2w2, s2w2);
  const float2 s2w5 = cmul(s2w4, s2w1);
  const float2 s2w6 = cmul(s2w4, s2w2);
  const float2 s2w7 = cmul(s2w4, s2w3);

  // ---- unpack-role constants ----
  const int f2i = t & 7, q = t >> 3, fu = f2i << 1;
  const int sk0 = swz(q);
  const int sm0 = swz((512 - q) & 511);
  const int sk1 = sk0 + 128;                    // swz(q+128) = swz(q)+128
  const int sm1 = (q == 0) ? 384 : (sm0 - 128); // swz(384-q)
  __sincosf((float)q * (-6.28318530717958647693f / 1024.f), &sn, &cs);
  const float2 tw0 = make_float2(cs, sn);
  const float2 tw1 = cmul(tw0, make_float2(0.70710678118654752440f,
                                           -0.70710678118654752440f));
  float* out_r = out;
  float* out_i = out + (size_t)16 * NBINS * NFRAMES;
  const int fr_u = f0 + fu;
  const size_t qrow = ((size_t)b * NBINS + q) * NFRAMES + fr_u;
  const size_t mrow = ((size_t)b * NBINS + (512 - q)) * NFRAMES + fr_u;
  const size_t erow = ((size_t)b * NBINS + 256) * NFRAMES + fr_u;
  const size_t STP  = (size_t)128 * NFRAMES;

  // ================= sub-tile A: frames f0 .. f0+15 =================
  float2 r[8];
  const int baseA = (f0 + wid) * HOP - 384;   // pad_left = 384
  LOADW(baseA, wdw == 0, r)
  FFT_BODY(z + (wid << 9), r)
  __syncthreads();

  // ================= overlap: load B early, store A under FFT B =====
  const int baseB = (f0 + 16 + wid) * HOP - 384;
  LOADW(baseB, wdw == 31, r)        // issued before stores; vmcnt in-order
  DO_UNPACK(z, 0)                   // A-stores posted, drain under FFT B
  FFT_BODY(z + 8192 + (wid << 9), r)
  __syncthreads();

  // ================= sub-tile B unpack =================
  DO_UNPACK(z + 8192, 16)
}

extern "C" void kernel_launch(void* const* d_in, const int* in_sizes, int n_in,
                              void* d_out, int out_size, void* d_ws, size_t ws_size,
                              hipStream_t stream) {
  const float* x = (const float*)d_in[0];
  const float* w = (const float*)d_in[1];
  float* out = (float*)d_out;
  (void)in_sizes; (void)n_in; (void)out_size; (void)d_ws; (void)ws_size;
  stft_kernel<<<dim3(512), dim3(1024), 0, stream>>>(x, w, out);
}

// Round 11
// 32.240 us; speedup vs baseline: 2.3302x; 1.1500x over previous
//
#include <hip/hip_runtime.h>

#define HOP      256
#define SAMPLES  262144
#define NBINS    513
#define NFRAMES  1024
#define FPB      16   // frames per block, one wave per frame

__device__ __forceinline__ float2 cmul(float2 a, float2 b) {
  return make_float2(a.x * b.x - a.y * b.y, a.x * b.y + a.y * b.x);
}
__device__ __forceinline__ float2 lds_ld(const float2* p, int bo) {
  return *(const float2*)((const char*)p + bo);
}
__device__ __forceinline__ void lds_st(float2* p, int bo, float2 v) {
  *(float2*)((char*)p + bo) = v;
}
// swizzle: c = (H<<6)|(M<<3)|L -> (H<<6)|((M^(H&1))<<3)|(L^M)
__device__ __forceinline__ int swz(int c) {
  int H = c >> 6, M = (c >> 3) & 7, L = c & 7;
  return (H << 6) | ((M ^ (H & 1)) << 3) | (L ^ M);
}

// 8-point DFT, natural-order in/out, W = e^{-2pi i/8}
__device__ __forceinline__ void fft8(float2 v[8]) {
  const float R = 0.70710678118654752440f;
  float2 s0 = make_float2(v[0].x + v[4].x, v[0].y + v[4].y);
  float2 d0 = make_float2(v[0].x - v[4].x, v[0].y - v[4].y);
  float2 s1 = make_float2(v[1].x + v[5].x, v[1].y + v[5].y);
  float2 d1 = make_float2(v[1].x - v[5].x, v[1].y - v[5].y);
  float2 s2 = make_float2(v[2].x + v[6].x, v[2].y + v[6].y);
  float2 d2 = make_float2(v[2].x - v[6].x, v[2].y - v[6].y);
  float2 s3 = make_float2(v[3].x + v[7].x, v[3].y + v[7].y);
  float2 d3 = make_float2(v[3].x - v[7].x, v[3].y - v[7].y);
  float2 e1 = make_float2(R * (d1.x + d1.y), R * (d1.y - d1.x));
  float2 e2 = make_float2(d2.y, -d2.x);
  float2 e3 = make_float2(R * (d3.y - d3.x), R * (-d3.x - d3.y));
  float2 p0 = make_float2(s0.x + s2.x, s0.y + s2.y);
  float2 q0 = make_float2(s0.x - s2.x, s0.y - s2.y);
  float2 p1 = make_float2(s1.x + s3.x, s1.y + s3.y);
  float2 q1 = make_float2(s1.x - s3.x, s1.y - s3.y);
  float2 q1t = make_float2(q1.y, -q1.x);
  float2 p2 = make_float2(d0.x + e2.x, d0.y + e2.y);
  float2 q2 = make_float2(d0.x - e2.x, d0.y - e2.y);
  float2 p3 = make_float2(e1.x + e3.x, e1.y + e3.y);
  float2 q3 = make_float2(e1.x - e3.x, e1.y - e3.y);
  float2 q3t = make_float2(q3.y, -q3.x);
  v[0] = make_float2(p0.x + p1.x, p0.y + p1.y);
  v[4] = make_float2(p0.x - p1.x, p0.y - p1.y);
  v[2] = make_float2(q0.x + q1t.x, q0.y + q1t.y);
  v[6] = make_float2(q0.x - q1t.x, q0.y - q1t.y);
  v[1] = make_float2(p2.x + p3.x, p2.y + p3.y);
  v[5] = make_float2(p2.x - p3.x, p2.y - p3.y);
  v[3] = make_float2(q2.x + q3t.x, q2.y + q3t.y);
  v[7] = make_float2(q2.x - q3t.x, q2.y - q3t.y);
}

// unpack one (frame, bin): ZP = frame base, KEY = frame xor-key, SK/SM slots
#define UNPK(ZP, KEY, SK, SM, TW, R1, I1, R2, I2) {                  \
    float2 Zk = lds_ld(ZP, ((SK) ^ (KEY)) << 3);                     \
    float2 Zm = lds_ld(ZP, ((SM) ^ (KEY)) << 3);                     \
    float xer  = 0.5f * (Zk.x + Zm.x);                               \
    float xei  = 0.5f * (Zk.y - Zm.y);                               \
    float xo_r = 0.5f * (Zk.y + Zm.y);                               \
    float xo_i = -0.5f * (Zk.x - Zm.x);                              \
    float ur = (TW).x * xo_r - (TW).y * xo_i;                        \
    float ui = (TW).x * xo_i + (TW).y * xo_r;                        \
    R1 = xer + ur; I1 = xei + ui; R2 = xer - ur; I2 = ui - xei; }

__global__ __launch_bounds__(1024, 8)   // VGPR<=64 -> 2 blocks/CU
void stft_kernel(const float* __restrict__ x, const float* __restrict__ win,
                 float* __restrict__ out) {
  __shared__ float2 z[FPB * 512];  // 64 KiB

  // phase-stagger probe: odd blocks delay ~4.5us so their unpack (store)
  // window anti-aligns with the even co-resident block's window.
  if (blockIdx.x & 1) {
    __builtin_amdgcn_s_sleep(127);
    __builtin_amdgcn_s_sleep(45);
  }

  const int t  = threadIdx.x;
  const int b  = blockIdx.x >> 6;
  const int f0 = (blockIdx.x & 63) * FPB;

  // ---------------- FFT phase: one wave per frame, all LDS intra-wave ------
  {
    const int w = t >> 6;     // wave = frame-in-tile
    const int u = t & 63;     // lane
    const int g = u >> 3, m2l = u & 7;
    float2* zf = z + (w << 9);

    // closed-form swizzled addresses (bytes), derived from swz():
    const int A0    = (g << 3) | (m2l ^ g);
    const int B1w_e = (A0 ^ w) << 3;                              // ex1 write, even k1
    const int B1w_o = B1w_e ^ 64;                                 //            odd k1
    const int C1    = (g << 6) | ((g & 1) << 3) | m2l;
    const int B1r   = (C1 ^ w) << 3;   // ex1 read / ex2 write: ^ (72*m1)
    const int D0    = (g << 6) | ((m2l ^ (g & 1)) << 3) | m2l;
    const int B2r   = (D0 ^ w) << 3;   // ex2 read: ^ (m<<3)
    const int F0    = (m2l << 3) | (g ^ m2l);
    const int B3_e  = (F0 ^ w) << 3;                              // st3 write, even j2
    const int B3_o  = B3_e ^ 64;                                  //            odd j2

    // ---- load + window (bounds check only in first/last tile) ----
    const float* xb = x + (size_t)b * SAMPLES;
    const int fr   = f0 + w;
    const int base = fr * HOP - 384;  // pad_left = 384
    float2 r[8];
    if (f0 != 0 && f0 != (NFRAMES - FPB)) {
      const float2* xc = (const float2*)(xb + base);
      const float2* wc = (const float2*)win;
#pragma unroll
      for (int n1 = 0; n1 < 8; ++n1) {
        float2 xv = xc[(n1 << 6) + u];
        float2 wv = wc[(n1 << 6) + u];
        r[n1] = make_float2(xv.x * wv.x, xv.y * wv.y);
      }
    } else {
#pragma unroll
      for (int n1 = 0; n1 < 8; ++n1) {
        int s = (n1 << 7) + 2 * u;
        int idx = base + s;
        float2 xv = make_float2(0.f, 0.f);
        if (idx >= 0 && idx < SAMPLES) xv = *(const float2*)(xb + idx);
        float2 wv = *(const float2*)(win + s);
        r[n1] = make_float2(xv.x * wv.x, xv.y * wv.y);
      }
    }

    // ---- stage 1: radix-8, twiddle W512^{u*k1} ----
    fft8(r);
    float sn, cs;
    __sincosf((float)u * (-6.28318530717958647693f / 512.f), &sn, &cs);
    {
      float2 w1 = make_float2(cs, sn);
      float2 w2 = cmul(w1, w1);
      float2 w3 = cmul(w2, w1);
      float2 w4 = cmul(w2, w2);
      r[1] = cmul(r[1], w1);
      r[2] = cmul(r[2], w2);
      r[3] = cmul(r[3], w3);
      r[4] = cmul(r[4], w4);
      r[5] = cmul(r[5], cmul(w4, w1));
      r[6] = cmul(r[6], cmul(w4, w2));
      r[7] = cmul(r[7], cmul(w4, w3));
    }
    lds_st(zf, B1w_e,        r[0]);
    lds_st(zf, B1w_o +  512, r[1]);
    lds_st(zf, B1w_e + 1024, r[2]);
    lds_st(zf, B1w_o + 1536, r[3]);
    lds_st(zf, B1w_e + 2048, r[4]);
    lds_st(zf, B1w_o + 2560, r[5]);
    lds_st(zf, B1w_e + 3072, r[6]);
    lds_st(zf, B1w_o + 3584, r[7]);

    // ex1 read: addr = B1r ^ 72*m1
    float2 y[8];
#pragma unroll
    for (int m1 = 0; m1 < 8; ++m1) y[m1] = lds_ld(zf, B1r ^ (72 * m1));

    // ---- stage 2: radix-8, twiddle W64^{m2l*j1} ----
    fft8(y);
    __sincosf((float)m2l * (-6.28318530717958647693f / 64.f), &sn, &cs);
    {
      float2 w1 = make_float2(cs, sn);
      float2 w2 = cmul(w1, w1);
      float2 w3 = cmul(w2, w1);
      float2 w4 = cmul(w2, w2);
      y[1] = cmul(y[1], w1);
      y[2] = cmul(y[2], w2);
      y[3] = cmul(y[3], w3);
      y[4] = cmul(y[4], w4);
      y[5] = cmul(y[5], cmul(w4, w1));
      y[6] = cmul(y[6], cmul(w4, w2));
      y[7] = cmul(y[7], cmul(w4, w3));
    }
    // ex2 write: same 8 addresses as ex1 read (in-place along m1/j1)
#pragma unroll
    for (int j1 = 0; j1 < 8; ++j1) lds_st(zf, B1r ^ (72 * j1), y[j1]);

    // ex2 read: addr = B2r ^ (m<<3)
    float2 h[8];
#pragma unroll
    for (int m = 0; m < 8; ++m) h[m] = lds_ld(zf, B2r ^ (m << 3));

    // ---- stage 3 + natural-order store: addr = base_even/odd + j2*512 ----
    fft8(h);
    lds_st(zf, B3_e,        h[0]);
    lds_st(zf, B3_o +  512, h[1]);
    lds_st(zf, B3_e + 1024, h[2]);
    lds_st(zf, B3_o + 1536, h[3]);
    lds_st(zf, B3_e + 2048, h[4]);
    lds_st(zf, B3_o + 2560, h[5]);
    lds_st(zf, B3_e + 3072, h[6]);
    lds_st(zf, B3_o + 3584, h[7]);
  }
  __syncthreads();

  // -------- unpack: frame-pair per thread, float2 stores, 2 bin-steps ------
  {
    const int f2i = t & 7;        // frame-pair index: 8 lanes span 16 frames
    const int q   = t >> 3;       // bin 0..127
    const int f   = f2i << 1;
    const int fr  = f0 + f;
    const float2* zp0 = z + (f << 9);
    const float2* zp1 = z + ((f + 1) << 9);

    const int sk0 = swz(q);
    const int sm0 = swz((512 - q) & 511);
    const int sk1 = sk0 + 128;                   // swz(q+128) = swz(q)+128
    const int sm1 = (q == 0) ? 384 : (sm0 - 128);// swz(384-q); q=0 -> swz(384)

    float sn, cs;
    __sincosf((float)q * (-6.28318530717958647693f / 1024.f), &sn, &cs);
    const float2 tw0 = make_float2(cs, sn);
    const float2 tw1 = cmul(tw0, make_float2(0.70710678118654752440f,
                                             -0.70710678118654752440f));
    float* out_r = out;
    float* out_i = out + (size_t)16 * NBINS * NFRAMES;
    const size_t o1 = ((size_t)b * NBINS + q) * NFRAMES + fr;
    const size_t o2 = ((size_t)b * NBINS + (512 - q)) * NFRAMES + fr;
    const size_t STP = (size_t)128 * NFRAMES;

    // ---- k = q ----
    {
      float r1a, i1a, r2a, i2a, r1b, i1b, r2b, i2b;
      UNPK(zp0, f,     sk0, sm0, tw0, r1a, i1a, r2a, i2a)
      UNPK(zp1, f + 1, sk0, sm0, tw0, r1b, i1b, r2b, i2b)
      *(float2*)(out_r + o1) = make_float2(r1a, r1b);
      *(float2*)(out_i + o1) = make_float2(i1a, i1b);
      *(float2*)(out_r + o2) = make_float2(r2a, r2b);
      *(float2*)(out_i + o2) = make_float2(i2a, i2b);
    }
    // ---- k = q + 128 ----
    {
      float r1a, i1a, r2a, i2a, r1b, i1b, r2b, i2b;
      UNPK(zp0, f,     sk1, sm1, tw1, r1a, i1a, r2a, i2a)
      UNPK(zp1, f + 1, sk1, sm1, tw1, r1b, i1b, r2b, i2b)
      *(float2*)(out_r + o1 + STP) = make_float2(r1a, r1b);
      *(float2*)(out_i + o1 + STP) = make_float2(i1a, i1b);
      *(float2*)(out_r + o2 - STP) = make_float2(r2a, r2b);
      *(float2*)(out_i + o2 - STP) = make_float2(i2a, i2b);
    }
    // ---- edge bin 256: X[256] = conj(Z[256]) ----
    if (q == 0) {
      float2 Za = lds_ld(zp0, (256 ^ f) << 3);
      float2 Zb = lds_ld(zp1, (256 ^ (f + 1)) << 3);
      const size_t o6 = ((size_t)b * NBINS + 256) * NFRAMES + fr;
      *(float2*)(out_r + o6) = make_float2(Za.x, Zb.x);
      *(float2*)(out_i + o6) = make_float2(-Za.y, -Zb.y);
    }
  }
}

extern "C" void kernel_launch(void* const* d_in, const int* in_sizes, int n_in,
                              void* d_out, int out_size, void* d_ws, size_t ws_size,
                              hipStream_t stream) {
  const float* x = (const float*)d_in[0];
  const float* w = (const float*)d_in[1];
  float* out = (float*)d_out;
  (void)in_sizes; (void)n_in; (void)out_size; (void)d_ws; (void)ws_size;
  stft_kernel<<<dim3(1024), dim3(1024), 0, stream>>>(x, w, out);
}

// Round 12
// 24.850 us; speedup vs baseline: 3.0232x; 1.2974x over previous
//
#include <hip/hip_runtime.h>

#define HOP      256
#define SAMPLES  262144
#define NBINS    513
#define NFRAMES  1024
#define FPB      16   // frames per block; 8 waves x 2 frames each

__device__ __forceinline__ float2 cmul(float2 a, float2 b) {
  return make_float2(a.x * b.x - a.y * b.y, a.x * b.y + a.y * b.x);
}
__device__ __forceinline__ float2 lds_ld(const float2* p, int bo) {
  return *(const float2*)((const char*)p + bo);
}
__device__ __forceinline__ void lds_st(float2* p, int bo, float2 v) {
  *(float2*)((char*)p + bo) = v;
}
// swizzle: c = (H<<6)|(M<<3)|L -> (H<<6)|((M^(H&1))<<3)|(L^M)
__device__ __forceinline__ int swz(int c) {
  int H = c >> 6, M = (c >> 3) & 7, L = c & 7;
  return (H << 6) | ((M ^ (H & 1)) << 3) | (L ^ M);
}

// 8-point DFT, natural-order in/out, W = e^{-2pi i/8}
__device__ __forceinline__ void fft8(float2 v[8]) {
  const float R = 0.70710678118654752440f;
  float2 s0 = make_float2(v[0].x + v[4].x, v[0].y + v[4].y);
  float2 d0 = make_float2(v[0].x - v[4].x, v[0].y - v[4].y);
  float2 s1 = make_float2(v[1].x + v[5].x, v[1].y + v[5].y);
  float2 d1 = make_float2(v[1].x - v[5].x, v[1].y - v[5].y);
  float2 s2 = make_float2(v[2].x + v[6].x, v[2].y + v[6].y);
  float2 d2 = make_float2(v[2].x - v[6].x, v[2].y - v[6].y);
  float2 s3 = make_float2(v[3].x + v[7].x, v[3].y + v[7].y);
  float2 d3 = make_float2(v[3].x - v[7].x, v[3].y - v[7].y);
  float2 e1 = make_float2(R * (d1.x + d1.y), R * (d1.y - d1.x));
  float2 e2 = make_float2(d2.y, -d2.x);
  float2 e3 = make_float2(R * (d3.y - d3.x), R * (-d3.x - d3.y));
  float2 p0 = make_float2(s0.x + s2.x, s0.y + s2.y);
  float2 q0 = make_float2(s0.x - s2.x, s0.y - s2.y);
  float2 p1 = make_float2(s1.x + s3.x, s1.y + s3.y);
  float2 q1 = make_float2(s1.x - s3.x, s1.y - s3.y);
  float2 q1t = make_float2(q1.y, -q1.x);
  float2 p2 = make_float2(d0.x + e2.x, d0.y + e2.y);
  float2 q2 = make_float2(d0.x - e2.x, d0.y - e2.y);
  float2 p3 = make_float2(e1.x + e3.x, e1.y + e3.y);
  float2 q3 = make_float2(e1.x - e3.x, e1.y - e3.y);
  float2 q3t = make_float2(q3.y, -q3.x);
  v[0] = make_float2(p0.x + p1.x, p0.y + p1.y);
  v[4] = make_float2(p0.x - p1.x, p0.y - p1.y);
  v[2] = make_float2(q0.x + q1t.x, q0.y + q1t.y);
  v[6] = make_float2(q0.x - q1t.x, q0.y - q1t.y);
  v[1] = make_float2(p2.x + p3.x, p2.y + p3.y);
  v[5] = make_float2(p2.x - p3.x, p2.y - p3.y);
  v[3] = make_float2(q2.x + q3t.x, q2.y + q3t.y);
  v[7] = make_float2(q2.x - q3t.x, q2.y - q3t.y);
}

// stage 1: fft8 + W512^{u*k1} twiddles + ex1 write (E/O byte bases)
#define FFT_S1(R, ZF, E1, O1) {                                          \
    fft8(R);                                                             \
    R[1] = cmul(R[1], s1w1);  R[2] = cmul(R[2], s1w2);                   \
    R[3] = cmul(R[3], s1w3);  R[4] = cmul(R[4], s1w4);                   \
    R[5] = cmul(R[5], s1w5);  R[6] = cmul(R[6], s1w6);                   \
    R[7] = cmul(R[7], s1w7);                                             \
    lds_st(ZF, (E1),        R[0]);                                       \
    lds_st(ZF, (O1) +  512, R[1]);                                       \
    lds_st(ZF, (E1) + 1024, R[2]);                                       \
    lds_st(ZF, (O1) + 1536, R[3]);                                       \
    lds_st(ZF, (E1) + 2048, R[4]);                                       \
    lds_st(ZF, (O1) + 2560, R[5]);                                       \
    lds_st(ZF, (E1) + 3072, R[6]);                                       \
    lds_st(ZF, (O1) + 3584, R[7]);                                       \
  }

// stage 2: ex1 read + fft8 + W64^{m2l*j1} twiddles + ex2 write (in place)
#define FFT_S2(Y, ZF, BR) {                                              \
    _Pragma("unroll")                                                    \
    for (int m1 = 0; m1 < 8; ++m1) Y[m1] = lds_ld(ZF, (BR) ^ (72 * m1)); \
    fft8(Y);                                                             \
    Y[1] = cmul(Y[1], s2w1);  Y[2] = cmul(Y[2], s2w2);                   \
    Y[3] = cmul(Y[3], s2w3);  Y[4] = cmul(Y[4], s2w4);                   \
    Y[5] = cmul(Y[5], s2w5);  Y[6] = cmul(Y[6], s2w6);                   \
    Y[7] = cmul(Y[7], s2w7);                                             \
    _Pragma("unroll")                                                    \
    for (int j1 = 0; j1 < 8; ++j1) lds_st(ZF, (BR) ^ (72 * j1), Y[j1]);  \
  }

// stage 3: ex2 read + fft8 + natural-order store
#define FFT_S3(H, ZF, B2, E3, O3) {                                      \
    _Pragma("unroll")                                                    \
    for (int m = 0; m < 8; ++m) H[m] = lds_ld(ZF, (B2) ^ (m << 3));      \
    fft8(H);                                                             \
    lds_st(ZF, (E3),        H[0]);                                       \
    lds_st(ZF, (O3) +  512, H[1]);                                       \
    lds_st(ZF, (E3) + 1024, H[2]);                                       \
    lds_st(ZF, (O3) + 1536, H[3]);                                       \
    lds_st(ZF, (E3) + 2048, H[4]);                                       \
    lds_st(ZF, (O3) + 2560, H[5]);                                       \
    lds_st(ZF, (E3) + 3072, H[6]);                                       \
    lds_st(ZF, (O3) + 3584, H[7]);                                       \
  }

// unpack one (frame, bin): ZP = frame base, KEY = frame xor-key, SK/SM slots
#define UNPK(ZP, KEY, SK, SM, TW, R1, I1, R2, I2) {                  \
    float2 Zk = lds_ld(ZP, ((SK) ^ (KEY)) << 3);                     \
    float2 Zm = lds_ld(ZP, ((SM) ^ (KEY)) << 3);                     \
    float xer  = 0.5f * (Zk.x + Zm.x);                               \
    float xei  = 0.5f * (Zk.y - Zm.y);                               \
    float xo_r = 0.5f * (Zk.y + Zm.y);                               \
    float xo_i = -0.5f * (Zk.x - Zm.x);                              \
    float ur = (TW).x * xo_r - (TW).y * xo_i;                        \
    float ui = (TW).x * xo_i + (TW).y * xo_r;                        \
    R1 = xer + ur; I1 = xei + ui; R2 = xer - ur; I2 = ui - xei; }

__global__ __launch_bounds__(512, 4)   // VGPR<=128; 2 blocks/CU by LDS
void stft_kernel(const float* __restrict__ x, const float* __restrict__ win,
                 float* __restrict__ out) {
  __shared__ float2 z[FPB * 512];  // 64 KiB
  const int t  = threadIdx.x;
  const int b  = blockIdx.x >> 6;
  const int f0 = (blockIdx.x & 63) * FPB;

  // ---------------- FFT phase: each wave handles frames w and w+8 ----------
  {
    const int w = t >> 6;     // wave -> frame A = f0+w, frame B = f0+w+8
    const int u = t & 63;     // lane
    const int g = u >> 3, m2l = u & 7;
    float2* zfA = z + (w << 9);
    float2* zfB = z + ((w + 8) << 9);

    // closed-form swizzled byte addresses (frame A key = w); frame B key =
    // w^8 -> all byte offsets ^ 64 (which swaps each E/O pair).
    const int A0    = (g << 3) | (m2l ^ g);
    const int B1w_e = (A0 ^ w) << 3;
    const int B1w_o = B1w_e ^ 64;
    const int C1    = (g << 6) | ((g & 1) << 3) | m2l;
    const int B1r   = (C1 ^ w) << 3;   // ex1 read / ex2 write: ^ (72*m1)
    const int D0    = (g << 6) | ((m2l ^ (g & 1)) << 3) | m2l;
    const int B2r   = (D0 ^ w) << 3;   // ex2 read: ^ (m<<3)
    const int F0    = (m2l << 3) | (g ^ m2l);
    const int B3_e  = (F0 ^ w) << 3;
    const int B3_o  = B3_e ^ 64;

    // ---- load both frames early (HBM latency overlaps twiddle setup) ----
    const float* xb = x + (size_t)b * SAMPLES;
    const int baseA = (f0 + w) * HOP - 384;        // pad_left = 384
    const int baseB = baseA + 8 * HOP;
    const float2* wc = (const float2*)win;
    float2 ra[8], rb[8];
    if (f0 != 0) {
      const float2* xc = (const float2*)(xb + baseA);
#pragma unroll
      for (int n1 = 0; n1 < 8; ++n1) ra[n1] = xc[(n1 << 6) + u];
    } else {
#pragma unroll
      for (int n1 = 0; n1 < 8; ++n1) {
        int idx = baseA + (n1 << 7) + 2 * u;
        ra[n1] = make_float2(0.f, 0.f);
        if (idx >= 0) ra[n1] = *(const float2*)(xb + idx);
      }
    }
    if (f0 != (NFRAMES - FPB)) {
      const float2* xc = (const float2*)(xb + baseB);
#pragma unroll
      for (int n1 = 0; n1 < 8; ++n1) rb[n1] = xc[(n1 << 6) + u];
    } else {
#pragma unroll
      for (int n1 = 0; n1 < 8; ++n1) {
        int idx = baseB + (n1 << 7) + 2 * u;
        rb[n1] = make_float2(0.f, 0.f);
        if (idx < SAMPLES) rb[n1] = *(const float2*)(xb + idx);
      }
    }

    // hoisted stage twiddles (lane-only; shared by both frames)
    float sn, cs;
    __sincosf((float)u * (-6.28318530717958647693f / 512.f), &sn, &cs);
    const float2 s1w1 = make_float2(cs, sn);
    const float2 s1w2 = cmul(s1w1, s1w1);
    const float2 s1w3 = cmul(s1w2, s1w1);
    const float2 s1w4 = cmul(s1w2, s1w2);
    const float2 s1w5 = cmul(s1w4, s1w1);
    const float2 s1w6 = cmul(s1w4, s1w2);
    const float2 s1w7 = cmul(s1w4, s1w3);
    __sincosf((float)m2l * (-6.28318530717958647693f / 64.f), &sn, &cs);
    const float2 s2w1 = make_float2(cs, sn);
    const float2 s2w2 = cmul(s2w1, s2w1);
    const float2 s2w3 = cmul(s2w2, s2w1);
    const float2 s2w4 = cmul(s2w2, s2w2);
    const float2 s2w5 = cmul(s2w4, s2w1);
    const float2 s2w6 = cmul(s2w4, s2w2);
    const float2 s2w7 = cmul(s2w4, s2w3);

    // window both frames (8 shared window loads)
#pragma unroll
    for (int n1 = 0; n1 < 8; ++n1) {
      float2 wv = wc[(n1 << 6) + u];
      ra[n1] = make_float2(ra[n1].x * wv.x, ra[n1].y * wv.y);
      rb[n1] = make_float2(rb[n1].x * wv.x, rb[n1].y * wv.y);
    }

    // interleaved dual-frame pipeline: each DS wait of one frame is covered
    // by the other frame's fft8+twiddle VALU block.
    FFT_S1(ra, zfA, B1w_e, B1w_o)
    FFT_S1(rb, zfB, B1w_o, B1w_e)              // ^64: E/O swapped
    {
      float2 y[8];
      FFT_S2(y, zfA, B1r)
      float2 y2[8];
      FFT_S2(y2, zfB, B1r ^ 64)
    }
    {
      float2 h[8];
      FFT_S3(h, zfA, B2r, B3_e, B3_o)
      float2 h2[8];
      FFT_S3(h2, zfB, B2r ^ 64, B3_o, B3_e)    // ^64: E/O swapped
    }
  }
  __syncthreads();

  // -------- unpack: frame-pair per thread, qq in {q, q+64} -----------------
  {
    const int f2i = t & 7;        // frame-pair index: 8 lanes span 16 frames
    const int q   = t >> 3;       // bin residue 0..63
    const int f   = f2i << 1;
    const int fr  = f0 + f;
    const float2* zp0 = z + (f << 9);
    const float2* zp1 = z + ((f + 1) << 9);
    float* out_r = out;
    float* out_i = out + (size_t)16 * NBINS * NFRAMES;
    const size_t STP = (size_t)128 * NFRAMES;

    float sn, cs;
    __sincosf((float)q * (-6.28318530717958647693f / 1024.f), &sn, &cs);
    const float2 twq = make_float2(cs, sn);

#pragma unroll
    for (int hh = 0; hh < 2; ++hh) {
      const int qq  = q + (hh << 6);
      const int sk0 = swz(qq);
      const int sm0 = swz((512 - qq) & 511);
      const int sk1 = sk0 + 128;                    // swz(qq+128)
      const int sm1 = (qq == 0) ? 384 : (sm0 - 128);// swz(384-qq)
      // tw(q+64) = tw(q) * e^{-i*pi/8}; tw(k+128) = tw(k) * e^{-i*pi/4}
      const float2 tw0 = hh ? cmul(twq, make_float2(0.92387953251128675613f,
                                                    -0.38268343236508977173f))
                            : twq;
      const float2 tw1 = cmul(tw0, make_float2(0.70710678118654752440f,
                                               -0.70710678118654752440f));
      const size_t o1 = ((size_t)b * NBINS + qq) * NFRAMES + fr;
      const size_t o2 = ((size_t)b * NBINS + (512 - qq)) * NFRAMES + fr;

      // ---- k = qq ----
      {
        float r1a, i1a, r2a, i2a, r1b, i1b, r2b, i2b;
        UNPK(zp0, f,     sk0, sm0, tw0, r1a, i1a, r2a, i2a)
        UNPK(zp1, f + 1, sk0, sm0, tw0, r1b, i1b, r2b, i2b)
        *(float2*)(out_r + o1) = make_float2(r1a, r1b);
        *(float2*)(out_i + o1) = make_float2(i1a, i1b);
        *(float2*)(out_r + o2) = make_float2(r2a, r2b);
        *(float2*)(out_i + o2) = make_float2(i2a, i2b);
      }
      // ---- k = qq + 128 ----
      {
        float r1a, i1a, r2a, i2a, r1b, i1b, r2b, i2b;
        UNPK(zp0, f,     sk1, sm1, tw1, r1a, i1a, r2a, i2a)
        UNPK(zp1, f + 1, sk1, sm1, tw1, r1b, i1b, r2b, i2b)
        *(float2*)(out_r + o1 + STP) = make_float2(r1a, r1b);
        *(float2*)(out_i + o1 + STP) = make_float2(i1a, i1b);
        *(float2*)(out_r + o2 - STP) = make_float2(r2a, r2b);
        *(float2*)(out_i + o2 - STP) = make_float2(i2a, i2b);
      }
    }
    // ---- edge bin 256: X[256] = conj(Z[256]) ----
    if (q == 0) {
      float2 Za = lds_ld(zp0, (256 ^ f) << 3);
      float2 Zb = lds_ld(zp1, (256 ^ (f + 1)) << 3);
      const size_t o6 = ((size_t)b * NBINS + 256) * NFRAMES + fr;
      *(float2*)(out_r + o6) = make_float2(Za.x, Zb.x);
      *(float2*)(out_i + o6) = make_float2(-Za.y, -Zb.y);
    }
  }
}

extern "C" void kernel_launch(void* const* d_in, const int* in_sizes, int n_in,
                              void* d_out, int out_size, void* d_ws, size_t ws_size,
                              hipStream_t stream) {
  const float* x = (const float*)d_in[0];
  const float* w = (const float*)d_in[1];
  float* out = (float*)d_out;
  (void)in_sizes; (void)n_in; (void)out_size; (void)d_ws; (void)ws_size;
  stft_kernel<<<dim3(1024), dim3(512), 0, stream>>>(x, w, out);
}